// Round 9
// baseline (1791.551 us; speedup 1.0000x reference)
//
#include <hip/hip_runtime.h>
#include <math.h>
#include <stdint.h>

#define BB 64
#define SS 512
#define HH 1024
#define TT 21

// DPP-based partial reduce within row of 16, then cross-row shuffles.
template <int CTRL>
__device__ __forceinline__ float dpp_add(float v) {
  int t = __builtin_amdgcn_update_dpp(0, __float_as_int(v), CTRL, 0xF, 0xF, true);
  return v + __int_as_float(t);
}
__device__ __forceinline__ float wave_sum(float v) {
  v = dpp_add<0x121>(v);  // row_ror:1
  v = dpp_add<0x122>(v);  // row_ror:2
  v = dpp_add<0x124>(v);  // row_ror:4
  v = dpp_add<0x128>(v);  // row_ror:8
  v += __shfl_xor(v, 16);
  v += __shfl_xor(v, 32);
  return v;
}

#define DOT4(A, H, WV)    \
  A = fmaf(H.x, WV.x, A); \
  A = fmaf(H.y, WV.y, A); \
  A = fmaf(H.z, WV.z, A); \
  A = fmaf(H.w, WV.w, A)

#define RLF(V, K) __int_as_float(__builtin_amdgcn_readlane(__float_as_int(V), K))

// ---------------- Fused kernel: emissions producer + CRF + Viterbi + loss --
// Round-9: clock/heater theory dead; scan wall (~190us) is a single-wave
// latency floor that no body variant moves, and cross-step reassociation
// risks integer pred flips -> scans stay bit-exact serial. Instead remove
// k_emis (~160us) + launch gaps entirely: one block per batch, 8 waves.
//   wave 0: CRF scan + fused loss (verbatim round-8 arithmetic)
//   wave 1: Viterbi (verbatim round-8 arithmetic)
//   waves 2-7: 336 producer lanes compute 16 emission rows x 21 tags per
//     iteration straight into sE, 2 chunks ahead of the consumers.
// Producer per-output arithmetic is bit-exact to the verified k_emis
// (8 q-accumulators, i-ascending DOT4, pairwise combine tree, +bias).
// Safety: producer writes rows >= 16*it; consumer reads rows <= 16*it-8
// (incl. prefetch) -> disjoint; one __syncthreads per iteration.
__global__ __launch_bounds__(512) void k_fused(const float* __restrict__ hs,
                                               const int* __restrict__ mask,
                                               const int* __restrict__ labels,
                                               const float* __restrict__ W,
                                               const float* __restrict__ bias,
                                               const float* __restrict__ trans,
                                               const float* __restrict__ sv,
                                               const float* __restrict__ ev,
                                               float* __restrict__ outv,
                                               float* __restrict__ pred) {
  __shared__ float sE[SS * TT];         // 42 KiB
  __shared__ unsigned long long mb[9];  // ballot words (+0 pad)
  __shared__ unsigned char bp[SS][32];  // 16 KiB (viterbi)
  __shared__ unsigned char sTag[SS];    // 0.5 KiB (viterbi)
  const int tid = threadIdx.x;
  const int wid = tid >> 6;
  const int ln = tid & 63;
  const int b = blockIdx.x;
  const bool act = (ln < TT);
  const int jj = act ? ln : 0;

  // wave 0 stages the mask ballot words before the pipeline starts
  if (wid == 0) {
#pragma unroll
    for (int w = 0; w < 8; ++w) {
      unsigned long long bm = __ballot(mask[b * SS + w * 64 + ln] != 0);
      if (ln == 0) mb[w] = bm;
    }
    if (ln == 0) mb[8] = 0ull;
  }

  // consumer persistent state (TV = E for CRF wave, Tc for VIT wave)
  float TV[TT];
  float st = 0.f, C = 0.f;
  float nxtv[8];

#define CRF_STEP(P)                                                           \
  {                                                                           \
    const int mk = (int)((swin >> (shb + (P))) & 1ull);                       \
    const float ge_t = ge[P];                                                 \
    const float v0 = RLF(st, 0), v1 = RLF(st, 1), v2 = RLF(st, 2);            \
    const float v3 = RLF(st, 3), v4 = RLF(st, 4), v5 = RLF(st, 5);            \
    const float v6 = RLF(st, 6), v7 = RLF(st, 7), v8 = RLF(st, 8);            \
    const float v9 = RLF(st, 9), v10 = RLF(st, 10), v11 = RLF(st, 11);        \
    const float v12 = RLF(st, 12), v13 = RLF(st, 13), v14 = RLF(st, 14);      \
    const float v15 = RLF(st, 15), v16 = RLF(st, 16), v17 = RLF(st, 17);      \
    const float v18 = RLF(st, 18), v19 = RLF(st, 19), v20 = RLF(st, 20);      \
    float scale = 1.0f;                                                       \
    if ((P) == 7) {                                                           \
      float m = fmaxf(fmaxf(fmaxf(v0, v1), fmaxf(v2, v3)),                    \
                      fmaxf(fmaxf(v4, v5), fmaxf(v6, v7)));                   \
      m = fmaxf(m, fmaxf(fmaxf(v8, v9), fmaxf(v10, v11)));                    \
      m = fmaxf(m, fmaxf(fmaxf(v12, v13), fmaxf(v14, v15)));                  \
      m = fmaxf(m, fmaxf(fmaxf(v16, v17), fmaxf(v18, v19)));                  \
      m = fmaxf(m, v20);                                                      \
      int ex = (int)((__float_as_uint(m) >> 23) & 255u) - 127;                \
      scale = __uint_as_float((unsigned)(127 - ex) << 23);                    \
      C += (float)ex * 0.6931471805599453f;                                   \
      st *= scale;                                                            \
    }                                                                         \
    float q0 = v0 * TV[0], q1 = v1 * TV[1], q2 = v2 * TV[2];                  \
    q0 = fmaf(v3, TV[3], q0);   q1 = fmaf(v4, TV[4], q1);   q2 = fmaf(v5, TV[5], q2);   \
    q0 = fmaf(v6, TV[6], q0);   q1 = fmaf(v7, TV[7], q1);   q2 = fmaf(v8, TV[8], q2);   \
    q0 = fmaf(v9, TV[9], q0);   q1 = fmaf(v10, TV[10], q1); q2 = fmaf(v11, TV[11], q2); \
    q0 = fmaf(v12, TV[12], q0); q1 = fmaf(v13, TV[13], q1); q2 = fmaf(v14, TV[14], q2); \
    q0 = fmaf(v15, TV[15], q0); q1 = fmaf(v16, TV[16], q1); q2 = fmaf(v17, TV[17], q2); \
    q0 = fmaf(v18, TV[18], q0); q1 = fmaf(v19, TV[19], q1); q2 = fmaf(v20, TV[20], q2); \
    float vn = ((q0 + q1 + q2) * scale) * ge_t;                               \
    st = (act && mk) ? vn : st;                                               \
  }

#define ARGSTEP(BV, BI, VAL, IDX)          \
  {                                        \
    float x_ = (VAL) + TV[IDX];            \
    if (x_ > BV) { BV = x_; BI = (IDX); }  \
  }
#define VIT_STEP(P)                                                           \
  {                                                                           \
    const int mk = (int)((swin >> (shb + (P))) & 1ull);                       \
    const float e = cur[P];                                                   \
    const float s0 = RLF(st, 0), s1 = RLF(st, 1), s2 = RLF(st, 2);            \
    const float s3 = RLF(st, 3), s4 = RLF(st, 4), s5 = RLF(st, 5);            \
    const float s6 = RLF(st, 6), s7 = RLF(st, 7), s8 = RLF(st, 8);            \
    const float s9 = RLF(st, 9), s10 = RLF(st, 10), s11 = RLF(st, 11);        \
    const float s12 = RLF(st, 12), s13 = RLF(st, 13), s14 = RLF(st, 14);      \
    const float s15 = RLF(st, 15), s16 = RLF(st, 16), s17 = RLF(st, 17);      \
    const float s18 = RLF(st, 18), s19 = RLF(st, 19), s20 = RLF(st, 20);      \
    float b0v, b1v, b2v;                                                      \
    int i0, i1, i2;                                                           \
    b0v = s0 + TV[0]; i0 = 0;                                                 \
    b1v = s1 + TV[1]; i1 = 1;                                                 \
    b2v = s2 + TV[2]; i2 = 2;                                                 \
    ARGSTEP(b0v, i0, s3, 3);   ARGSTEP(b1v, i1, s4, 4);   ARGSTEP(b2v, i2, s5, 5);    \
    ARGSTEP(b0v, i0, s6, 6);   ARGSTEP(b1v, i1, s7, 7);   ARGSTEP(b2v, i2, s8, 8);    \
    ARGSTEP(b0v, i0, s9, 9);   ARGSTEP(b1v, i1, s10, 10); ARGSTEP(b2v, i2, s11, 11);  \
    ARGSTEP(b0v, i0, s12, 12); ARGSTEP(b1v, i1, s13, 13); ARGSTEP(b2v, i2, s14, 14);  \
    ARGSTEP(b0v, i0, s15, 15); ARGSTEP(b1v, i1, s16, 16); ARGSTEP(b2v, i2, s17, 17);  \
    ARGSTEP(b0v, i0, s18, 18); ARGSTEP(b1v, i1, s19, 19); ARGSTEP(b2v, i2, s20, 20);  \
    float best = b0v;                                                         \
    int bi = i0;                                                              \
    if (b1v > best || (b1v == best && i1 < bi)) { best = b1v; bi = i1; }      \
    if (b2v > best || (b2v == best && i2 < bi)) { best = b2v; bi = i2; }      \
    float ns = best + e;                                                      \
    st = (act && mk) ? ns : st;                                               \
    if (act) bp[t0 + (P)][ln] = (unsigned char)(mk ? bi : ln);                \
  }

#pragma unroll 1
  for (int it = 0; it < 34; ++it) {
    if (wid >= 2) {
      // ---- producers: 2 chunks (16 rows x 21 tags) per iteration ----
      const int p = tid - 128;
      if (it <= 31 && p < 336) {
        const int r = p / 21;
        const int tg = p - r * 21;
        const int row = it * 16 + r;
        const float4* hp = (const float4*)(hs + ((size_t)b * SS + row) * HH);
        const float4* wp = (const float4*)(W + (size_t)tg * HH);
        float a[8] = {0.f, 0.f, 0.f, 0.f, 0.f, 0.f, 0.f, 0.f};
#pragma unroll 2
        for (int i = 0; i < 32; ++i) {
#pragma unroll
          for (int q = 0; q < 8; ++q) {
            const float4 h4 = hp[i * 8 + q];
            const float4 w4 = wp[i * 8 + q];
            DOT4(a[q], h4, w4);
          }
        }
        // identical combine tree to the verified k_emis
        float s = ((a[0] + a[1]) + (a[2] + a[3])) + ((a[4] + a[5]) + (a[6] + a[7]));
        sE[row * TT + tg] = s + bias[tg];
      }
    } else if (wid == 0) {
      // ---- CRF consumer ----
      if (it == 2) {
#pragma unroll
        for (int i2 = 0; i2 < TT; ++i2) TV[i2] = __expf(trans[i2 * TT + jj]);
        st = act ? __expf(sv[jj] + sE[jj]) : 0.f;
        C = 0.f;
#pragma unroll
        for (int k = 0; k < 8; ++k) nxtv[k] = sE[(1 + k) * TT + jj];
      }
      if (it >= 2) {
#pragma unroll 1
        for (int u = 0; u < 2; ++u) {
          const int s = 2 * it - 4 + u;
          const int w = s >> 3;
          const unsigned long long wa = mb[w], wb2 = mb[w + 1];
          const unsigned long long winv = (wa >> 1) | (wb2 << 63);
          const unsigned wlo = __builtin_amdgcn_readfirstlane((unsigned)winv);
          const unsigned whi = __builtin_amdgcn_readfirstlane((unsigned)(winv >> 32));
          const unsigned long long swin = ((unsigned long long)whi << 32) | wlo;
          const int shb = (s & 7) << 3;
          const int t0 = s * 8 + 1;
          float cur[8], ge[8];
#pragma unroll
          for (int k = 0; k < 8; ++k) cur[k] = nxtv[k];
#pragma unroll
          for (int k = 0; k < 8; ++k) ge[k] = __expf(cur[k]);
#pragma unroll
          for (int k = 0; k < 8; ++k) {
            int tl = t0 + 8 + k;
            tl = (tl < SS) ? tl : (SS - 1);
            nxtv[k] = sE[tl * TT + jj];
          }
#pragma unroll
          for (int p = 0; p < 7; ++p) { CRF_STEP(p); }
          if (s < 63) { CRF_STEP(7); }  // step t=8(s+1) incl. renorm
        }
      }
    } else if (wid == 1) {
      // ---- Viterbi consumer ----
      if (it == 2) {
#pragma unroll
        for (int i2 = 0; i2 < TT; ++i2) TV[i2] = trans[i2 * TT + jj];
        st = act ? (sv[jj] + sE[jj]) : -3.0e38f;
#pragma unroll
        for (int k = 0; k < 8; ++k) nxtv[k] = sE[(1 + k) * TT + jj];
      }
      if (it >= 2) {
#pragma unroll 1
        for (int u = 0; u < 2; ++u) {
          const int s = 2 * it - 4 + u;
          const int w = s >> 3;
          const unsigned long long wa = mb[w], wb2 = mb[w + 1];
          const unsigned long long winv = (wa >> 1) | (wb2 << 63);
          const unsigned wlo = __builtin_amdgcn_readfirstlane((unsigned)winv);
          const unsigned whi = __builtin_amdgcn_readfirstlane((unsigned)(winv >> 32));
          const unsigned long long swin = ((unsigned long long)whi << 32) | wlo;
          const int shb = (s & 7) << 3;
          const int t0 = s * 8 + 1;
          float cur[8];
#pragma unroll
          for (int k = 0; k < 8; ++k) cur[k] = nxtv[k];
#pragma unroll
          for (int k = 0; k < 8; ++k) {
            int tl = t0 + 8 + k;
            tl = (tl < SS) ? tl : (SS - 1);
            nxtv[k] = sE[tl * TT + jj];
          }
#pragma unroll
          for (int p = 0; p < 7; ++p) { VIT_STEP(p); }
          if (s < 63) { VIT_STEP(7); }
        }
      }
    }
    __syncthreads();
  }

  // ---- CRF tail: logZ + fused numerator/loss (sE fully populated) ----
  if (wid == 0) {
    float wv = act ? st * __expf(ev[jj]) : 0.f;
#pragma unroll
    for (int d = 32; d >= 1; d >>= 1) wv += __shfl_xor(wv, d);
    const float logZv = C + __logf(wv);
    int cnt = 0;
#pragma unroll
    for (int w = 0; w < 8; ++w) cnt += (int)__popcll(mb[w]);
    const int* lab = labels + b * SS;
    float p = 0.f;
    for (int t = ln; t < SS; t += 64) {
      if (t >= 1) {
        const int lp = lab[t - 1];
        const int lc = lab[t];
        const float mk = (float)((mb[t >> 6] >> (t & 63)) & 1ull);
        p += mk * (trans[lp * TT + lc] + sE[t * TT + lc]);
      }
    }
    p = wave_sum(p);
    if (ln == 0) {
      const int l0 = lab[0];
      float numer = p + sv[l0] + sE[l0];
      numer += ev[lab[cnt - 1]];
      atomicAdd(outv, logZv - numer);  // loss = sum_b (logZ - numerator)
    }
  }

  // ---- Viterbi tail: final argmax, backtrace, copy-out ----
  if (wid == 1) {
    float fsv = act ? (st + ev[jj]) : -3.0e38f;
    int idx = ln;
#pragma unroll
    for (int d = 32; d >= 1; d >>= 1) {
      float ov = __shfl_xor(fsv, d);
      int oi = __shfl_xor(idx, d);
      bool take = (ov > fsv) || (ov == fsv && oi < idx);
      fsv = take ? ov : fsv;
      idx = take ? oi : idx;
    }
    if (ln == 0) sTag[SS - 1] = (unsigned char)idx;
  }
  __syncthreads();
  if (wid == 1 && ln == 0) {
    int tag = (int)sTag[SS - 1];
    for (int t = SS - 1; t >= 1; --t) {
      tag = bp[t][tag];
      sTag[t - 1] = (unsigned char)tag;
    }
  }
  __syncthreads();
  if (wid == 1) {
    for (int i = ln; i < SS; i += 64) {
      pred[(size_t)b * SS + i] = (float)(mask[b * SS + i] ? (int)sTag[i] : 0);
    }
  }
}

extern "C" void kernel_launch(void* const* d_in, const int* in_sizes, int n_in,
                              void* d_out, int out_size, void* d_ws, size_t ws_size,
                              hipStream_t stream) {
  const float* hs = (const float*)d_in[0];
  const int* msk = (const int*)d_in[1];
  const int* lab = (const int*)d_in[2];
  const float* W = (const float*)d_in[3];
  const float* bias = (const float*)d_in[4];
  const float* trans = (const float*)d_in[5];
  const float* sv = (const float*)d_in[6];
  const float* ev = (const float*)d_in[7];
  float* out = (float*)d_out;

  hipMemsetAsync(d_out, 0, 4, stream);  // zero the loss accumulator
  k_fused<<<64, 512, 0, stream>>>(hs, msk, lab, W, bias, trans, sv, ev, out, out + 1);
}

// Round 10
// 727.590 us; speedup vs baseline: 2.4623x; 2.4623x over previous
//
#include <hip/hip_runtime.h>
#include <math.h>
#include <stdint.h>

#define BB 64
#define SS 512
#define HH 1024
#define TT 21

// DPP-based partial reduce within row of 16, then cross-row shuffles.
template <int CTRL>
__device__ __forceinline__ float dpp_add(float v) {
  int t = __builtin_amdgcn_update_dpp(0, __float_as_int(v), CTRL, 0xF, 0xF, true);
  return v + __int_as_float(t);
}
__device__ __forceinline__ float wave_sum(float v) {
  v = dpp_add<0x121>(v);  // row_ror:1
  v = dpp_add<0x122>(v);  // row_ror:2
  v = dpp_add<0x124>(v);  // row_ror:4
  v = dpp_add<0x128>(v);  // row_ror:8
  v += __shfl_xor(v, 16);
  v += __shfl_xor(v, 32);
  return v;
}

#define DOT4(A, H, WV)    \
  A = fmaf(H.x, WV.x, A); \
  A = fmaf(H.y, WV.y, A); \
  A = fmaf(H.z, WV.z, A); \
  A = fmaf(H.w, WV.w, A)

#define RLF(V, K) __int_as_float(__builtin_amdgcn_readlane(__float_as_int(V), K))

// ---------------- Single fused kernel ----------------
// Round-10: round-9's producer failed on GEOMETRY (q was a loop index ->
// 21 uncoalesced W transactions/instruction, 66MB refetch, 1646us), not on
// the fusion idea. New: two clean phases, no lockstep pipeline.
//  Phase A (all 8 waves): this batch's emissions into sE with the VERIFIED
//   k_emis geometry (q=lane&7 -> 128B coalesced h, broadcast W) and
//   bit-exact per-output fp order (i-ascending DOT4 per q; pairwise q-tree
//   via shfl_xor 1/2/4 == ((q0+q1)+(q2+q3))+((q4+q5)+(q6+q7))).
//  Phase B: verbatim round-8 scan bodies; CRF blocks (0-63) also do the
//   fused loss; VIT blocks (64-127) do viterbi + backtrace + copyout.
// Barriers are block-uniform (all waves execute them).
__global__ __launch_bounds__(512) void k_all(const float* __restrict__ hs,
                                             const int* __restrict__ mask,
                                             const int* __restrict__ labels,
                                             const float* __restrict__ W,
                                             const float* __restrict__ bias,
                                             const float* __restrict__ trans,
                                             const float* __restrict__ sv,
                                             const float* __restrict__ ev,
                                             float* __restrict__ outv,
                                             float* __restrict__ pred) {
  __shared__ float sE[SS * TT];         // 42 KiB
  __shared__ unsigned long long mb[9];  // ballot words (+0 pad)
  __shared__ unsigned char bp[SS][32];  // 16 KiB (viterbi blocks)
  __shared__ unsigned char sTag[SS];    // 0.5 KiB (viterbi blocks)
  const int tid = threadIdx.x;
  const int wid = tid >> 6;
  const int ln = tid & 63;
  const int b = blockIdx.x & 63;
  const bool isCRF = (blockIdx.x < 64);

  // ---- Phase A: emissions for batch b into sE (all 8 waves) ----
  {
    const int q = ln & 7;
    const int rsub = ln >> 3;
#pragma unroll 1
    for (int pass = 0; pass < 8; ++pass) {
      const int row = pass * 64 + wid * 8 + rsub;
      const float4* hp = (const float4*)(hs + ((size_t)b * SS + row) * HH);
      float acc[TT];
#pragma unroll
      for (int t = 0; t < TT; ++t) acc[t] = 0.f;
      float4 h = hp[q];  // i = 0 prefetched
#pragma unroll 2
      for (int i = 0; i < 32; ++i) {
        const float4 hc = h;
        if (i < 31) h = hp[(i + 1) * 8 + q];
        const float* wb = W + i * 32 + q * 4;
#pragma unroll
        for (int tg = 0; tg < TT; ++tg) {
          const float4 w4 = *(const float4*)(wb + (size_t)tg * HH);
          DOT4(acc[tg], hc, w4);
        }
      }
#pragma unroll
      for (int tg = 0; tg < TT; ++tg) {
        float s = acc[tg];
        s += __shfl_xor(s, 1);  // (q0+q1),(q2+q3),...
        s += __shfl_xor(s, 2);  // (q0+q1)+(q2+q3),...
        s += __shfl_xor(s, 4);  // full pairwise tree (bit-exact to k_emis)
        if (q == 0) sE[row * TT + tg] = s + bias[tg];
      }
    }
  }
  // mask ballot words (wave 0)
  if (wid == 0) {
#pragma unroll
    for (int w = 0; w < 8; ++w) {
      unsigned long long bm = __ballot(mask[b * SS + w * 64 + ln] != 0);
      if (ln == 0) mb[w] = bm;
    }
    if (ln == 0) mb[8] = 0ull;
  }
  __syncthreads();

  const bool act = (ln < TT);
  const int jj = act ? ln : 0;

#define CRF_STEP(P, SHB)                                                      \
  {                                                                           \
    const int mk = (int)((swin >> ((SHB) + (P))) & 1ull);                     \
    const float ge_t = ge[P];                                                 \
    const float v0 = RLF(v, 0), v1 = RLF(v, 1), v2 = RLF(v, 2);               \
    const float v3 = RLF(v, 3), v4 = RLF(v, 4), v5 = RLF(v, 5);               \
    const float v6 = RLF(v, 6), v7 = RLF(v, 7), v8 = RLF(v, 8);               \
    const float v9 = RLF(v, 9), v10 = RLF(v, 10), v11 = RLF(v, 11);           \
    const float v12 = RLF(v, 12), v13 = RLF(v, 13), v14 = RLF(v, 14);         \
    const float v15 = RLF(v, 15), v16 = RLF(v, 16), v17 = RLF(v, 17);         \
    const float v18 = RLF(v, 18), v19 = RLF(v, 19), v20 = RLF(v, 20);         \
    float scale = 1.0f;                                                       \
    if ((P) == 7) {                                                           \
      float m = fmaxf(fmaxf(fmaxf(v0, v1), fmaxf(v2, v3)),                    \
                      fmaxf(fmaxf(v4, v5), fmaxf(v6, v7)));                   \
      m = fmaxf(m, fmaxf(fmaxf(v8, v9), fmaxf(v10, v11)));                    \
      m = fmaxf(m, fmaxf(fmaxf(v12, v13), fmaxf(v14, v15)));                  \
      m = fmaxf(m, fmaxf(fmaxf(v16, v17), fmaxf(v18, v19)));                  \
      m = fmaxf(m, v20);                                                      \
      int ex = (int)((__float_as_uint(m) >> 23) & 255u) - 127;                \
      scale = __uint_as_float((unsigned)(127 - ex) << 23);                    \
      C += (float)ex * 0.6931471805599453f;                                   \
      v *= scale;                                                             \
    }                                                                         \
    float q0 = v0 * E[0], q1 = v1 * E[1], q2 = v2 * E[2];                     \
    q0 = fmaf(v3, E[3], q0);   q1 = fmaf(v4, E[4], q1);   q2 = fmaf(v5, E[5], q2);   \
    q0 = fmaf(v6, E[6], q0);   q1 = fmaf(v7, E[7], q1);   q2 = fmaf(v8, E[8], q2);   \
    q0 = fmaf(v9, E[9], q0);   q1 = fmaf(v10, E[10], q1); q2 = fmaf(v11, E[11], q2); \
    q0 = fmaf(v12, E[12], q0); q1 = fmaf(v13, E[13], q1); q2 = fmaf(v14, E[14], q2); \
    q0 = fmaf(v15, E[15], q0); q1 = fmaf(v16, E[16], q1); q2 = fmaf(v17, E[17], q2); \
    q0 = fmaf(v18, E[18], q0); q1 = fmaf(v19, E[19], q1); q2 = fmaf(v20, E[20], q2); \
    float vn = ((q0 + q1 + q2) * scale) * ge_t;                               \
    v = (act && mk) ? vn : v;                                                 \
  }

#define ARGSTEP(BV, BI, VAL, IDX)          \
  {                                        \
    float x_ = (VAL) + Tc[IDX];            \
    if (x_ > BV) { BV = x_; BI = (IDX); }  \
  }
#define VIT_STEP(P, SHB, TCUR)                                                \
  {                                                                           \
    const int mk = (int)((swin >> ((SHB) + (P))) & 1ull);                     \
    const float e = cur[P];                                                   \
    const float s0 = RLF(sc, 0), s1 = RLF(sc, 1), s2 = RLF(sc, 2);            \
    const float s3 = RLF(sc, 3), s4 = RLF(sc, 4), s5 = RLF(sc, 5);            \
    const float s6 = RLF(sc, 6), s7 = RLF(sc, 7), s8 = RLF(sc, 8);            \
    const float s9 = RLF(sc, 9), s10 = RLF(sc, 10), s11 = RLF(sc, 11);        \
    const float s12 = RLF(sc, 12), s13 = RLF(sc, 13), s14 = RLF(sc, 14);      \
    const float s15 = RLF(sc, 15), s16 = RLF(sc, 16), s17 = RLF(sc, 17);      \
    const float s18 = RLF(sc, 18), s19 = RLF(sc, 19), s20 = RLF(sc, 20);      \
    float b0v, b1v, b2v;                                                      \
    int i0, i1, i2;                                                           \
    b0v = s0 + Tc[0]; i0 = 0;                                                 \
    b1v = s1 + Tc[1]; i1 = 1;                                                 \
    b2v = s2 + Tc[2]; i2 = 2;                                                 \
    ARGSTEP(b0v, i0, s3, 3);   ARGSTEP(b1v, i1, s4, 4);   ARGSTEP(b2v, i2, s5, 5);    \
    ARGSTEP(b0v, i0, s6, 6);   ARGSTEP(b1v, i1, s7, 7);   ARGSTEP(b2v, i2, s8, 8);    \
    ARGSTEP(b0v, i0, s9, 9);   ARGSTEP(b1v, i1, s10, 10); ARGSTEP(b2v, i2, s11, 11);  \
    ARGSTEP(b0v, i0, s12, 12); ARGSTEP(b1v, i1, s13, 13); ARGSTEP(b2v, i2, s14, 14);  \
    ARGSTEP(b0v, i0, s15, 15); ARGSTEP(b1v, i1, s16, 16); ARGSTEP(b2v, i2, s17, 17);  \
    ARGSTEP(b0v, i0, s18, 18); ARGSTEP(b1v, i1, s19, 19); ARGSTEP(b2v, i2, s20, 20);  \
    float best = b0v;                                                         \
    int bi = i0;                                                              \
    if (b1v > best || (b1v == best && i1 < bi)) { best = b1v; bi = i1; }      \
    if (b2v > best || (b2v == best && i2 < bi)) { best = b2v; bi = i2; }      \
    float ns = best + e;                                                      \
    sc = (act && mk) ? ns : sc;                                               \
    if (act) bp[TCUR][ln] = (unsigned char)(mk ? bi : ln);                    \
  }

  if (isCRF && wid == 0) {
    // ---- CRF logsumexp scan (exp domain, v = exp(alpha - C)) ----
    float E[TT];
#pragma unroll
    for (int i = 0; i < TT; ++i) E[i] = __expf(trans[i * TT + jj]);
    float v = act ? __expf(sv[jj] + sE[jj]) : 0.f;
    float C = 0.f;
    float nxtv[8];
#pragma unroll
    for (int k = 0; k < 8; ++k) nxtv[k] = sE[(1 + k) * TT + jj];

#pragma unroll 1
    for (int w = 0; w < 8; ++w) {
      const unsigned long long wa = mb[w], wb2 = mb[w + 1];
      const unsigned long long winv = (wa >> 1) | (wb2 << 63);
      const unsigned wlo = __builtin_amdgcn_readfirstlane((unsigned)winv);
      const unsigned whi = __builtin_amdgcn_readfirstlane((unsigned)(winv >> 32));
      const unsigned long long swin = ((unsigned long long)whi << 32) | wlo;
      const int nci = (w < 7) ? 8 : 7;
#pragma unroll 1
      for (int ci = 0; ci < nci; ++ci) {
        const int t0 = ((w << 3) + ci) * 8 + 1;
        float cur[8], ge[8];
#pragma unroll
        for (int k = 0; k < 8; ++k) cur[k] = nxtv[k];
#pragma unroll
        for (int k = 0; k < 8; ++k) ge[k] = __expf(cur[k]);
#pragma unroll
        for (int k = 0; k < 8; ++k) {
          int tl = t0 + 8 + k;
          tl = (tl < SS) ? tl : (SS - 1);
          nxtv[k] = sE[tl * TT + jj];
        }
        const int shb = ci << 3;
#pragma unroll
        for (int p = 0; p < 8; ++p) { CRF_STEP(p, shb); }
      }
      if (w == 7) {  // tail chunk: t = 505..511 (no renorm steps)
        float cur[8], ge[8];
#pragma unroll
        for (int k = 0; k < 7; ++k) cur[k] = nxtv[k];
#pragma unroll
        for (int k = 0; k < 7; ++k) ge[k] = __expf(cur[k]);
#pragma unroll
        for (int p = 0; p < 7; ++p) { CRF_STEP(p, 56); }
      }
    }
    float wv = act ? v * __expf(ev[jj]) : 0.f;
#pragma unroll
    for (int d = 32; d >= 1; d >>= 1) wv += __shfl_xor(wv, d);
    const float logZv = C + __logf(wv);

    // ---- fused numerator + loss (emissions read from LDS) ----
    int cnt = 0;
#pragma unroll
    for (int w = 0; w < 8; ++w) cnt += (int)__popcll(mb[w]);
    const int* lab = labels + b * SS;
    float p = 0.f;
    for (int t = ln; t < SS; t += 64) {
      if (t >= 1) {
        const int lp = lab[t - 1];
        const int lc = lab[t];
        const float mk = (float)((mb[t >> 6] >> (t & 63)) & 1ull);
        p += mk * (trans[lp * TT + lc] + sE[t * TT + lc]);
      }
    }
    p = wave_sum(p);
    if (ln == 0) {
      const int l0 = lab[0];
      float numer = p + sv[l0] + sE[l0];
      numer += ev[lab[cnt - 1]];
      atomicAdd(outv, logZv - numer);  // loss = sum_b (logZ - numerator)
    }
  } else if (!isCRF && wid == 0) {
    // ---- Viterbi main (verbatim round-8 body) ----
    float Tc[TT];
#pragma unroll
    for (int i = 0; i < TT; ++i) Tc[i] = trans[i * TT + jj];
    float sc = act ? (sv[jj] + sE[jj]) : -3.0e38f;
    float nxtv[8];
#pragma unroll
    for (int k = 0; k < 8; ++k) nxtv[k] = sE[(1 + k) * TT + jj];

#pragma unroll 1
    for (int w = 0; w < 8; ++w) {
      const unsigned long long wa = mb[w], wb2 = mb[w + 1];
      const unsigned long long winv = (wa >> 1) | (wb2 << 63);
      const unsigned wlo = __builtin_amdgcn_readfirstlane((unsigned)winv);
      const unsigned whi = __builtin_amdgcn_readfirstlane((unsigned)(winv >> 32));
      const unsigned long long swin = ((unsigned long long)whi << 32) | wlo;
      const int nci = (w < 7) ? 8 : 7;
#pragma unroll 1
      for (int ci = 0; ci < nci; ++ci) {
        const int t0 = ((w << 3) + ci) * 8 + 1;
        float cur[8];
#pragma unroll
        for (int k = 0; k < 8; ++k) cur[k] = nxtv[k];
#pragma unroll
        for (int k = 0; k < 8; ++k) {
          int tl = t0 + 8 + k;
          tl = (tl < SS) ? tl : (SS - 1);
          nxtv[k] = sE[tl * TT + jj];
        }
        const int shb = ci << 3;
#pragma unroll
        for (int p = 0; p < 8; ++p) { VIT_STEP(p, shb, t0 + p); }
      }
      if (w == 7) {  // tail chunk: t = 505..511
        float cur[8];
#pragma unroll
        for (int k = 0; k < 7; ++k) cur[k] = nxtv[k];
#pragma unroll
        for (int p = 0; p < 7; ++p) { VIT_STEP(p, 56, 505 + p); }
      }
    }
    float fsv = act ? (sc + ev[jj]) : -3.0e38f;
    int idx = ln;
#pragma unroll
    for (int d = 32; d >= 1; d >>= 1) {
      float ov = __shfl_xor(fsv, d);
      int oi = __shfl_xor(idx, d);
      bool take = (ov > fsv) || (ov == fsv && oi < idx);
      fsv = take ? ov : fsv;
      idx = take ? oi : idx;
    }
    if (ln == 0) sTag[SS - 1] = (unsigned char)idx;
  }

  // ---- uniform tail barriers (all waves of every block) ----
  __syncthreads();
  if (!isCRF && wid == 0 && ln == 0) {
    int tag = (int)sTag[SS - 1];
    for (int t = SS - 1; t >= 1; --t) {
      tag = bp[t][tag];
      sTag[t - 1] = (unsigned char)tag;
    }
  }
  __syncthreads();
  if (!isCRF) {
    // coalesced copy-out with all 512 threads
    for (int i = tid; i < SS; i += 512) {
      pred[(size_t)b * SS + i] = (float)(mask[b * SS + i] ? (int)sTag[i] : 0);
    }
  }
#undef VIT_STEP
#undef ARGSTEP
#undef CRF_STEP
}

extern "C" void kernel_launch(void* const* d_in, const int* in_sizes, int n_in,
                              void* d_out, int out_size, void* d_ws, size_t ws_size,
                              hipStream_t stream) {
  const float* hs = (const float*)d_in[0];
  const int* msk = (const int*)d_in[1];
  const int* lab = (const int*)d_in[2];
  const float* W = (const float*)d_in[3];
  const float* bias = (const float*)d_in[4];
  const float* trans = (const float*)d_in[5];
  const float* sv = (const float*)d_in[6];
  const float* ev = (const float*)d_in[7];
  float* out = (float*)d_out;

  hipMemsetAsync(d_out, 0, 4, stream);  // zero the loss accumulator
  k_all<<<128, 512, 0, stream>>>(hs, msk, lab, W, bias, trans, sv, ev, out, out + 1);
}

// Round 11
// 426.026 us; speedup vs baseline: 4.2053x; 1.7079x over previous
//
#include <hip/hip_runtime.h>
#include <math.h>
#include <stdint.h>

#define BB 64
#define SS 512
#define HH 1024
#define TT 21

// DPP-based partial reduce within row of 16, then cross-row shuffles.
template <int CTRL>
__device__ __forceinline__ float dpp_add(float v) {
  int t = __builtin_amdgcn_update_dpp(0, __float_as_int(v), CTRL, 0xF, 0xF, true);
  return v + __int_as_float(t);
}
__device__ __forceinline__ float wave_sum(float v) {
  v = dpp_add<0x121>(v);  // row_ror:1
  v = dpp_add<0x122>(v);  // row_ror:2
  v = dpp_add<0x124>(v);  // row_ror:4
  v = dpp_add<0x128>(v);  // row_ror:8
  v += __shfl_xor(v, 16);
  v += __shfl_xor(v, 32);
  return v;
}

#define DOT4(A, H, WV)    \
  A = fmaf(H.x, WV.x, A); \
  A = fmaf(H.y, WV.y, A); \
  A = fmaf(H.z, WV.z, A); \
  A = fmaf(H.w, WV.w, A)

// ---------------- Kernel 1: emissions = hs @ W^T + bias ----------------
// (r3 verbatim; block 0 also zeroes the loss accumulator -> memset dispatch
// is deleted. Stream order guarantees the zero lands before any scan atomic.)
__global__ __launch_bounds__(192, 4) void k_emis(const float* __restrict__ hs,
                                                 const float* __restrict__ W,
                                                 const float* __restrict__ bias,
                                                 float* __restrict__ emis,
                                                 float* __restrict__ outz) {
  if (blockIdx.x == 0 && threadIdx.x == 0) *outz = 0.f;
  __shared__ float part[192 * 14];  // 10752 B
  const int tid = threadIdx.x;
  const int q = tid & 7;     // K-phase 0..7 (covers k4 = 8*i + q)
  const int tmp = tid >> 3;  // 0..23
  const int tg = tmp % 3;    // t-group (7 tags each)
  const int rp = tmp / 3;    // row-pair 0..7 -> rows 2rp, 2rp+1
  const size_t row0 = (size_t)blockIdx.x * 16 + rp * 2;
  const float4* hp0 = (const float4*)(hs + row0 * HH);
  const float4* hp1 = (const float4*)(hs + (row0 + 1) * HH);
  const float* wb0 = W + (size_t)(tg * 7) * HH + q * 4;

  float a0[7] = {0.f, 0.f, 0.f, 0.f, 0.f, 0.f, 0.f};
  float a1[7] = {0.f, 0.f, 0.f, 0.f, 0.f, 0.f, 0.f};
  float4 h0 = hp0[q], h1 = hp1[q];  // i = 0 prefetched
#pragma unroll 2
  for (int i = 0; i < 32; ++i) {
    const float4 hc0 = h0, hc1 = h1;
    if (i < 31) {
      h0 = hp0[(i + 1) * 8 + q];
      h1 = hp1[(i + 1) * 8 + q];
    }
    const float* wb = wb0 + (size_t)i * 32;
#pragma unroll
    for (int lt = 0; lt < 7; ++lt) {
      const float4 w = *(const float4*)(wb + (size_t)lt * HH);
      DOT4(a0[lt], hc0, w);
      DOT4(a1[lt], hc1, w);
    }
  }
#pragma unroll
  for (int lt = 0; lt < 7; ++lt) {
    part[tid * 14 + lt] = a0[lt];
    part[tid * 14 + 7 + lt] = a1[lt];
  }
  __syncthreads();

  // combine 8 K-phases; 336 contiguous outputs per block -> coalesced
  for (int o = tid; o < 16 * TT; o += 192) {
    const int rr = o / TT;
    const int t = o - rr * TT;
    const int tg2 = t / 7;
    const int lt2 = t - tg2 * 7;
    const float* pp = part + (((rr >> 1) * 3 + tg2) * 8) * 14 + (rr & 1) * 7 + lt2;
    float s = ((pp[0] + pp[14]) + (pp[28] + pp[42])) +
              ((pp[56] + pp[70]) + (pp[84] + pp[98]));
    emis[(size_t)blockIdx.x * (16 * TT) + o] = s + bias[t];
  }
}

// ---------------- Kernel 2: merged CRF(+loss) / Viterbi scan ----------------
// r3 STREAMING structure verbatim (the 168us champion): emissions stream
// from global in 8-step register chunks prefetched one chunk ahead; masks
// via rolling int4 quads. CRF blocks (0-63) append the r0-verbatim loss
// tail (global emis reads, ~10us, hidden under the VIT side's max).
#define RLF(V, K) __int_as_float(__builtin_amdgcn_readlane(__float_as_int(V), K))

__global__ __launch_bounds__(64, 1) void k_scan(const float* __restrict__ emis,
                                                const int* __restrict__ mask,
                                                const int* __restrict__ labels,
                                                const float* __restrict__ trans,
                                                const float* __restrict__ sv,
                                                const float* __restrict__ ev,
                                                float* __restrict__ outv,
                                                float* __restrict__ pred) {
  __shared__ unsigned char bp[SS][32];  // 16 KiB (viterbi only)
  __shared__ unsigned char sTag[SS];    // 0.5 KiB (viterbi only)
  const int lane = threadIdx.x;
  const int j = lane;
  const bool act = (j < TT);
  const int jj = act ? j : 0;
  const int b = blockIdx.x & 63;
  const float* eb = emis + (size_t)b * SS * TT + jj;  // lane's emission column
  const int4* mq = (const int4*)(mask + b * SS);      // 128 aligned quads

  if (blockIdx.x < 64) {
    // ---- CRF logsumexp scan (exp domain, v = exp(alpha - C)) ----
    float E[TT];
#pragma unroll
    for (int i = 0; i < TT; ++i) E[i] = __expf(trans[i * TT + jj]);
    float v = act ? __expf(sv[jj] + eb[0]) : 0.f;
    float C = 0.f;
    float pre[8], cur[8];
#pragma unroll
    for (int k = 0; k < 8; ++k) pre[k] = eb[(size_t)(1 + k) * TT];  // chunk 0
    int4 qA = mq[0];
    for (int c = 0; c < 64; ++c) {
      const int base = c * 8;
      const int4 qB = mq[2 * c + 1];
      const int4 qC = mq[(2 * c + 2 < 128) ? (2 * c + 2) : 127];
      float ge[8];
#pragma unroll
      for (int k = 0; k < 8; ++k) cur[k] = pre[k];
#pragma unroll
      for (int k = 0; k < 8; ++k) ge[k] = __expf(cur[k]);
      if (c < 63) {
#pragma unroll
        for (int k = 0; k < 8; ++k) {
          int tl = base + 9 + k;
          tl = (tl < SS) ? tl : (SS - 1);
          pre[k] = eb[(size_t)tl * TT];
        }
      }
      const int mks[8] = {qA.y, qA.z, qA.w, qB.x, qB.y, qB.z, qB.w, qC.x};
#pragma unroll
      for (int p = 0; p < 8; ++p) {
        const int t = base + 1 + p;
        if (t >= SS) break;  // only last chunk, p == 7
        const int mk = mks[p];
        const float ge_t = ge[p];
        const float v0 = RLF(v, 0), v1 = RLF(v, 1), v2 = RLF(v, 2);
        const float v3 = RLF(v, 3), v4 = RLF(v, 4), v5 = RLF(v, 5);
        const float v6 = RLF(v, 6), v7 = RLF(v, 7), v8 = RLF(v, 8);
        const float v9 = RLF(v, 9), v10 = RLF(v, 10), v11 = RLF(v, 11);
        const float v12 = RLF(v, 12), v13 = RLF(v, 13), v14 = RLF(v, 14);
        const float v15 = RLF(v, 15), v16 = RLF(v, 16), v17 = RLF(v, 17);
        const float v18 = RLF(v, 18), v19 = RLF(v, 19), v20 = RLF(v, 20);
        float scale = 1.0f;
        if (p == 7) {  // t = 8(c+1): exactly the (t&7)==0 renorm sites
          float m = fmaxf(fmaxf(fmaxf(v0, v1), fmaxf(v2, v3)),
                          fmaxf(fmaxf(v4, v5), fmaxf(v6, v7)));
          m = fmaxf(m, fmaxf(fmaxf(v8, v9), fmaxf(v10, v11)));
          m = fmaxf(m, fmaxf(fmaxf(v12, v13), fmaxf(v14, v15)));
          m = fmaxf(m, fmaxf(fmaxf(v16, v17), fmaxf(v18, v19)));
          m = fmaxf(m, v20);
          int ex = (int)((__float_as_uint(m) >> 23) & 255u) - 127;
          scale = __uint_as_float((unsigned)(127 - ex) << 23);  // 2^-ex exact
          C += (float)ex * 0.6931471805599453f;
          v *= scale;  // keep masked lanes consistent with C
        }
        // q chains: identical summation order to the verified kernel
        float q0 = v0 * E[0], q1 = v1 * E[1], q2 = v2 * E[2];
        q0 = fmaf(v3, E[3], q0);   q1 = fmaf(v4, E[4], q1);   q2 = fmaf(v5, E[5], q2);
        q0 = fmaf(v6, E[6], q0);   q1 = fmaf(v7, E[7], q1);   q2 = fmaf(v8, E[8], q2);
        q0 = fmaf(v9, E[9], q0);   q1 = fmaf(v10, E[10], q1); q2 = fmaf(v11, E[11], q2);
        q0 = fmaf(v12, E[12], q0); q1 = fmaf(v13, E[13], q1); q2 = fmaf(v14, E[14], q2);
        q0 = fmaf(v15, E[15], q0); q1 = fmaf(v16, E[16], q1); q2 = fmaf(v17, E[17], q2);
        q0 = fmaf(v18, E[18], q0); q1 = fmaf(v19, E[19], q1); q2 = fmaf(v20, E[20], q2);
        float vn = ((q0 + q1 + q2) * scale) * ge_t;
        v = (act && mk) ? vn : v;
      }
      qA = qC;
    }
    float wv = act ? v * __expf(ev[jj]) : 0.f;
#pragma unroll
    for (int d = 32; d >= 1; d >>= 1) wv += __shfl_xor(wv, d);
    const float logZv = C + __logf(wv);

    // ---- fused loss tail (r0 k_loss arithmetic, verbatim order) ----
    float pacc = 0.f;
    int cnt = 0;
    for (int t = lane; t < SS; t += 64) {
      cnt += mask[b * SS + t] ? 1 : 0;
      if (t >= 1) {
        const int lp = labels[b * SS + t - 1];
        const int lc = labels[b * SS + t];
        const float mk = (float)mask[b * SS + t];
        pacc += mk * (trans[lp * TT + lc] + emis[((size_t)b * SS + t) * TT + lc]);
      }
    }
    pacc = wave_sum(pacc);
#pragma unroll
    for (int d = 32; d >= 1; d >>= 1) cnt += __shfl_xor(cnt, d);
    if (lane == 0) {
      const int l0 = labels[b * SS];
      float numer = pacc + sv[l0] + emis[(size_t)b * SS * TT + l0];
      numer += ev[labels[b * SS + cnt - 1]];
      atomicAdd(outv, logZv - numer);  // loss = sum_b (logZ - numerator)
    }
  } else {
    // ---- Viterbi: r3 streaming structure, argmax chains (verbatim) ----
    float Tc[TT];
#pragma unroll
    for (int i = 0; i < TT; ++i) Tc[i] = trans[i * TT + jj];
    float sc = act ? (sv[jj] + eb[0]) : -3.0e38f;
    float pre[8], cur[8];
#pragma unroll
    for (int k = 0; k < 8; ++k) pre[k] = eb[(size_t)(1 + k) * TT];
    int4 qA = mq[0];
    for (int c = 0; c < 64; ++c) {
      const int base = c * 8;
      const int4 qB = mq[2 * c + 1];
      const int4 qC = mq[(2 * c + 2 < 128) ? (2 * c + 2) : 127];
#pragma unroll
      for (int k = 0; k < 8; ++k) cur[k] = pre[k];
      if (c < 63) {
#pragma unroll
        for (int k = 0; k < 8; ++k) {
          int tl = base + 9 + k;
          tl = (tl < SS) ? tl : (SS - 1);
          pre[k] = eb[(size_t)tl * TT];
        }
      }
      const int mks[8] = {qA.y, qA.z, qA.w, qB.x, qB.y, qB.z, qB.w, qC.x};
#pragma unroll
      for (int p = 0; p < 8; ++p) {
        const int t = base + 1 + p;
        if (t >= SS) break;
        const int mk = mks[p];
        const float e = cur[p];
        const float s0 = RLF(sc, 0), s1 = RLF(sc, 1), s2 = RLF(sc, 2);
        const float s3 = RLF(sc, 3), s4 = RLF(sc, 4), s5 = RLF(sc, 5);
        const float s6 = RLF(sc, 6), s7 = RLF(sc, 7), s8 = RLF(sc, 8);
        const float s9 = RLF(sc, 9), s10 = RLF(sc, 10), s11 = RLF(sc, 11);
        const float s12 = RLF(sc, 12), s13 = RLF(sc, 13), s14 = RLF(sc, 14);
        const float s15 = RLF(sc, 15), s16 = RLF(sc, 16), s17 = RLF(sc, 17);
        const float s18 = RLF(sc, 18), s19 = RLF(sc, 19), s20 = RLF(sc, 20);
        float b0v, b1v, b2v;
        int i0, i1, i2;
#define ARGSTEP(BV, BI, VAL, IDX)          \
  {                                        \
    float x_ = (VAL) + Tc[IDX];            \
    if (x_ > BV) { BV = x_; BI = (IDX); }  \
  }
        b0v = s0 + Tc[0]; i0 = 0;
        b1v = s1 + Tc[1]; i1 = 1;
        b2v = s2 + Tc[2]; i2 = 2;
        ARGSTEP(b0v, i0, s3, 3);   ARGSTEP(b1v, i1, s4, 4);   ARGSTEP(b2v, i2, s5, 5);
        ARGSTEP(b0v, i0, s6, 6);   ARGSTEP(b1v, i1, s7, 7);   ARGSTEP(b2v, i2, s8, 8);
        ARGSTEP(b0v, i0, s9, 9);   ARGSTEP(b1v, i1, s10, 10); ARGSTEP(b2v, i2, s11, 11);
        ARGSTEP(b0v, i0, s12, 12); ARGSTEP(b1v, i1, s13, 13); ARGSTEP(b2v, i2, s14, 14);
        ARGSTEP(b0v, i0, s15, 15); ARGSTEP(b1v, i1, s16, 16); ARGSTEP(b2v, i2, s17, 17);
        ARGSTEP(b0v, i0, s18, 18); ARGSTEP(b1v, i1, s19, 19); ARGSTEP(b2v, i2, s20, 20);
#undef ARGSTEP
        // merge with first-index tie-break (matches jnp.argmax)
        float best = b0v;
        int bi = i0;
        if (b1v > best || (b1v == best && i1 < bi)) { best = b1v; bi = i1; }
        if (b2v > best || (b2v == best && i2 < bi)) { best = b2v; bi = i2; }
        float ns = best + e;
        sc = (act && mk) ? ns : sc;
        if (act) bp[t][j] = (unsigned char)(mk ? bi : j);
      }
      qA = qC;
    }
    float fsv = act ? (sc + ev[jj]) : -3.0e38f;
    int idx = j;
#pragma unroll
    for (int d = 32; d >= 1; d >>= 1) {
      float ov = __shfl_xor(fsv, d);
      int oi = __shfl_xor(idx, d);
      bool take = (ov > fsv) || (ov == fsv && oi < idx);
      fsv = take ? ov : fsv;
      idx = take ? oi : idx;
    }
    __syncthreads();
    if (lane == 0) {
      int tag = idx;
      sTag[SS - 1] = (unsigned char)tag;
      for (int t = SS - 1; t >= 1; --t) {
        tag = bp[t][tag];
        sTag[t - 1] = (unsigned char)tag;
      }
    }
    __syncthreads();
    // coalesced copy-out: pred = where(mask, tags, 0) as float
    for (int i = lane; i < SS; i += 64) {
      pred[(size_t)b * SS + i] = (float)(mask[b * SS + i] ? (int)sTag[i] : 0);
    }
  }
}

extern "C" void kernel_launch(void* const* d_in, const int* in_sizes, int n_in,
                              void* d_out, int out_size, void* d_ws, size_t ws_size,
                              hipStream_t stream) {
  const float* hs = (const float*)d_in[0];
  const int* msk = (const int*)d_in[1];
  const int* lab = (const int*)d_in[2];
  const float* W = (const float*)d_in[3];
  const float* bias = (const float*)d_in[4];
  const float* trans = (const float*)d_in[5];
  const float* sv = (const float*)d_in[6];
  const float* ev = (const float*)d_in[7];
  float* out = (float*)d_out;

  float* emis = (float*)d_ws;  // 64*512*21 floats

  // 2 dispatches total: k_emis zeroes out[0] (stream-ordered before the
  // scan's atomics), so the memset dispatch is gone.
  k_emis<<<2048, 192, 0, stream>>>(hs, W, bias, emis, out);
  k_scan<<<128, 64, 0, stream>>>(emis, msk, lab, trans, sv, ev, out, out + 1);
}